// Round 5
// baseline (4197.707 us; speedup 1.0000x reference)
//
#include <hip/hip_runtime.h>

#define DD 512
#define BB 64
#define VV 32000
#define TT 32
#define GRID 256
#define NTHR 512
#define NP 25
#define NTILE 500

typedef __attribute__((ext_vector_type(8))) short short8;
typedef __attribute__((ext_vector_type(4))) float f32x4;
typedef unsigned long long u64;
typedef unsigned int u32;

__device__ __forceinline__ float sigm(float x) { return 1.0f / (1.0f + __expf(-x)); }
__device__ __forceinline__ float ftanh(float x) {
  float e = __expf(2.0f * x);
  return 1.0f - 2.0f / (e + 1.0f);
}
__device__ __forceinline__ unsigned short f2bf(float f) {
  u32 u = __float_as_uint(f);
  u = (u + 0x7FFFu + ((u >> 16) & 1u)) >> 16;
  return (unsigned short)u;
}
__device__ __forceinline__ u64 pack4bf(float a, float b, float c, float d) {
  return (u64)f2bf(a) | ((u64)f2bf(b) << 16) | ((u64)f2bf(c) << 32) | ((u64)f2bf(d) << 48);
}
__device__ __forceinline__ u64 pack4bf4(float4 v) { return pack4bf(v.x, v.y, v.z, v.w); }

// ---- coherent (LLC round-trip) accessors for mutable cross-block state ----
__device__ __forceinline__ void st_u32(u32* p, u32 v) {
  __hip_atomic_store(p, v, __ATOMIC_RELAXED, __HIP_MEMORY_SCOPE_AGENT);
}
__device__ __forceinline__ u32 ld_u32c(const u32* p) {
  return __hip_atomic_load(p, __ATOMIC_RELAXED, __HIP_MEMORY_SCOPE_AGENT);
}
__device__ __forceinline__ void st_u64c(u64* p, u64 v) {
  __hip_atomic_store(p, v, __ATOMIC_RELAXED, __HIP_MEMORY_SCOPE_AGENT);
}
__device__ __forceinline__ u64 ld_u64c(const u64* p) {
  return __hip_atomic_load(p, __ATOMIC_RELAXED, __HIP_MEMORY_SCOPE_AGENT);
}
__device__ __forceinline__ void st_f32(float* p, float v) { st_u32((u32*)p, __float_as_uint(v)); }
__device__ __forceinline__ float ld_f32(const float* p) { return __uint_as_float(ld_u32c((const u32*)p)); }
__device__ __forceinline__ float2 u64_to_f2(u64 v) {
  float2 r; r.x = __uint_as_float((u32)v); r.y = __uint_as_float((u32)(v >> 32)); return r;
}
__device__ __forceinline__ u64 f2_to_u64(float a, float b) {
  return (u64)__float_as_uint(a) | ((u64)__float_as_uint(b) << 32);
}

__device__ const float INVFACT[NP] = {
  1.0f, 1.0f, 0.5f, 1.6666667e-1f, 4.1666667e-2f, 8.3333333e-3f, 1.3888889e-3f,
  1.9841270e-4f, 2.4801587e-5f, 2.7557319e-6f, 2.7557319e-7f, 2.5052108e-8f,
  2.0876757e-9f, 1.6059044e-10f, 1.1470746e-11f, 7.6471637e-13f, 4.7794773e-14f,
  2.8114573e-15f, 1.5619207e-16f, 8.2206352e-18f, 4.1103176e-19f, 1.9572941e-20f,
  8.8967914e-22f, 3.8681702e-23f, 1.6117376e-24f
};

struct CellS {
  float4 xs4[16][129];   // emb tile, row-padded +16B -> conflict-free  33024B
  float4 hs4[16][129];   // h tile                                     33024B
  float gp[4][16][32];   // K-split partials [ks][b][dl*4+g]            8192B
  float ggv[16][32];     // final gates                                 2048B
};
struct RecS {
  float fr[512], hs[512], wv[512], ctx[512], es[512];
  float mco[32], tco[32];
  float sred[8][32];
  float wred[16];
};
union SmemU { CellS cell; RecS rec; unsigned short ebf[64 * 520]; };

// ---- flag-array grid barrier (relaxed atomics only, leader+broadcast) ----
__device__ __forceinline__ void gridsync(u32* flags, u32* go, unsigned& epoch) {
  epoch++;
  asm volatile("s_waitcnt vmcnt(0) lgkmcnt(0)" ::: "memory");
  __syncthreads();
  int tid = threadIdx.x, bid = blockIdx.x;
  if (bid == 0) {
    if (tid == 0) st_u32(flags, epoch);
    int ok;
    do {
      u32 f = (tid < GRID) ? ld_u32c(flags + (size_t)tid * 32) : epoch;
      ok = __syncthreads_and((int)(f >= epoch));
    } while (!ok);
    if (tid == 0) st_u32(go, epoch);
  } else {
    if (tid == 0) {
      st_u32(flags + (size_t)bid * 32, epoch);
      while (ld_u32c(go) < epoch) __builtin_amdgcn_s_sleep(8);
    }
    __syncthreads();
  }
}

__global__ void bar_init_k(u32* bar) {
  int i = blockIdx.x * 512 + threadIdx.x;
  if (i < 8704) bar[i] = 0u;
}

// ---- phase A: LSTM cell, fp32 VALU. 256 blocks = 4 bg(16 b) x 64 cg(8 d).
// 512 thr: 4 K-splits x (16 b x 8 d), each thread computes 4 gate partials.
__device__ __forceinline__ void cell_phase(SmemU& SU, int bid,
    const float* __restrict__ Wih, const float* __restrict__ Whh,
    const float* __restrict__ bih, const float* __restrict__ bhh,
    const float* emb, const float* h_old, const float* c_old,
    float* h_new, float* c_new)
{
  CellS& S = SU.cell;
  int tid = threadIdx.x;
  int bg = bid >> 6, cg = bid & 63;
  int b0 = bg * 16, d0 = cg * 8;
  const u64* ep = (const u64*)emb;
  const u64* hp = (const u64*)h_old;
  for (int i = tid; i < 4096; i += NTHR) {
    int b = i >> 8, k2 = i & 255;
    float2 e2 = u64_to_f2(ld_u64c(ep + (size_t)(b0 + b) * 256 + k2));
    float2 h2 = u64_to_f2(ld_u64c(hp + (size_t)(b0 + b) * 256 + k2));
    ((float2*)&S.xs4[b][0])[k2] = e2;
    ((float2*)&S.hs4[b][0])[k2] = h2;
  }
  __syncthreads();
  {
    int ks = tid >> 7, sub = tid & 127, b = sub >> 3, dl = sub & 7;
    const float4* wi0 = (const float4*)(Wih + (size_t)(0 * 512 + d0 + dl) * 512) + ks * 32;
    const float4* wi1 = (const float4*)(Wih + (size_t)(1 * 512 + d0 + dl) * 512) + ks * 32;
    const float4* wi2 = (const float4*)(Wih + (size_t)(2 * 512 + d0 + dl) * 512) + ks * 32;
    const float4* wi3 = (const float4*)(Wih + (size_t)(3 * 512 + d0 + dl) * 512) + ks * 32;
    const float4* wh0 = (const float4*)(Whh + (size_t)(0 * 512 + d0 + dl) * 512) + ks * 32;
    const float4* wh1 = (const float4*)(Whh + (size_t)(1 * 512 + d0 + dl) * 512) + ks * 32;
    const float4* wh2 = (const float4*)(Whh + (size_t)(2 * 512 + d0 + dl) * 512) + ks * 32;
    const float4* wh3 = (const float4*)(Whh + (size_t)(3 * 512 + d0 + dl) * 512) + ks * 32;
    const float4* xr = &S.xs4[b][ks * 32];
    const float4* hr = &S.hs4[b][ks * 32];
    float a0 = 0.f, a1 = 0.f, a2 = 0.f, a3 = 0.f;
#pragma unroll 4
    for (int j = 0; j < 32; j++) {
      float4 xv = xr[j], hv = hr[j];
      float4 w;
      w = wi0[j]; a0 = fmaf(w.x, xv.x, a0); a0 = fmaf(w.y, xv.y, a0); a0 = fmaf(w.z, xv.z, a0); a0 = fmaf(w.w, xv.w, a0);
      w = wh0[j]; a0 = fmaf(w.x, hv.x, a0); a0 = fmaf(w.y, hv.y, a0); a0 = fmaf(w.z, hv.z, a0); a0 = fmaf(w.w, hv.w, a0);
      w = wi1[j]; a1 = fmaf(w.x, xv.x, a1); a1 = fmaf(w.y, xv.y, a1); a1 = fmaf(w.z, xv.z, a1); a1 = fmaf(w.w, xv.w, a1);
      w = wh1[j]; a1 = fmaf(w.x, hv.x, a1); a1 = fmaf(w.y, hv.y, a1); a1 = fmaf(w.z, hv.z, a1); a1 = fmaf(w.w, hv.w, a1);
      w = wi2[j]; a2 = fmaf(w.x, xv.x, a2); a2 = fmaf(w.y, xv.y, a2); a2 = fmaf(w.z, xv.z, a2); a2 = fmaf(w.w, xv.w, a2);
      w = wh2[j]; a2 = fmaf(w.x, hv.x, a2); a2 = fmaf(w.y, hv.y, a2); a2 = fmaf(w.z, hv.z, a2); a2 = fmaf(w.w, hv.w, a2);
      w = wi3[j]; a3 = fmaf(w.x, xv.x, a3); a3 = fmaf(w.y, xv.y, a3); a3 = fmaf(w.z, xv.z, a3); a3 = fmaf(w.w, xv.w, a3);
      w = wh3[j]; a3 = fmaf(w.x, hv.x, a3); a3 = fmaf(w.y, hv.y, a3); a3 = fmaf(w.z, hv.z, a3); a3 = fmaf(w.w, hv.w, a3);
    }
    S.gp[ks][b][dl * 4 + 0] = a0;
    S.gp[ks][b][dl * 4 + 1] = a1;
    S.gp[ks][b][dl * 4 + 2] = a2;
    S.gp[ks][b][dl * 4 + 3] = a3;
  }
  __syncthreads();
  {
    int b = tid >> 5, rg = tid & 31;
    float s = S.gp[0][b][rg] + S.gp[1][b][rg] + S.gp[2][b][rg] + S.gp[3][b][rg];
    int dl = rg >> 2, g = rg & 3;
    int r = g * 512 + d0 + dl;
    s += bih[r] + bhh[r];
    S.ggv[b][rg] = s;
  }
  __syncthreads();
  if (tid < 128) {
    int b = tid >> 3, dl = tid & 7;
    float gi = S.ggv[b][dl * 4 + 0];
    float gf = S.ggv[b][dl * 4 + 1];
    float gg = S.ggv[b][dl * 4 + 2];
    float go = S.ggv[b][dl * 4 + 3];
    size_t idx = (size_t)(b0 + b) * 512 + d0 + dl;
    float c2 = sigm(gf) * ld_f32(c_old + idx) + sigm(gi) * ftanh(gg);
    st_f32(c_new + idx, c2);
    st_f32(h_new + idx, sigm(go) * ftanh(c2));
  }
}

// ---- phase B (blocks 0..63): fp32 Taylor attention + zgemm + LN, per b ----
__device__ __forceinline__ void rec_phase(SmemU& SU, int b,
    const float* __restrict__ feats, const float* h, const float* Mb,
    const float* __restrict__ Whc, const float* __restrict__ bhc,
    const float* __restrict__ gam, const float* __restrict__ bet,
    float* emb, u64* ebfOut)
{
  RecS& S = SU.rec;
  int tid = threadIdx.x;
  if (tid < 256) {
    float2 h2 = u64_to_f2(ld_u64c((const u64*)h + (size_t)b * 256 + tid));
    S.hs[2 * tid] = h2.x; S.hs[2 * tid + 1] = h2.y;
  } else {
    int t2 = tid - 256;
    float2 f2 = ((const float2*)feats)[(size_t)b * 256 + t2];
    S.fr[2 * t2] = f2.x; S.fr[2 * t2 + 1] = f2.y;
  }
  if (tid < NP) S.mco[tid] = ld_f32(Mb + b * NP + tid);
  __syncthreads();
  float hj = S.hs[tid];
  float fi = S.fr[tid];
  // Z_j = sum_k M_k h_j^k  (thread = j);  wv_j = f_j / Z_j
  {
    float Z = S.mco[NP - 1];
#pragma unroll
    for (int k = NP - 2; k >= 0; k--) Z = fmaf(Z, hj, S.mco[k]);
    S.wv[tid] = fi / Z;
  }
  __syncthreads();
  // h-moments S_k = sum_j h_j^k wv_j
  {
    float part = S.wv[tid];
#pragma unroll
    for (int k = 0; k < NP; k++) {
      float v = part;
      v += __shfl_xor(v, 32); v += __shfl_xor(v, 16); v += __shfl_xor(v, 8);
      v += __shfl_xor(v, 4);  v += __shfl_xor(v, 2);  v += __shfl_xor(v, 1);
      if ((tid & 63) == 0) S.sred[tid >> 6][k] = v;
      part *= hj;
    }
  }
  __syncthreads();
  if (tid < NP) {
    float s = 0.f;
#pragma unroll
    for (int w = 0; w < 8; w++) s += S.sred[w][tid];
    S.tco[tid] = s * INVFACT[tid];
  }
  __syncthreads();
  // ctx_i = sum_k T_k f_i^k  (thread = i)
  {
    float C = S.tco[NP - 1];
#pragma unroll
    for (int k = NP - 2; k >= 0; k--) C = fmaf(C, fi, S.tco[k]);
    S.ctx[tid] = C;
  }
  __syncthreads();
  // z_d = [h|ctx] . Whc[d] + bhc[d]  (thread = d), fp32 rows from L2
  float z;
  {
    const float4* wrow = (const float4*)(Whc + (size_t)tid * 1024);
    const float4* hq = (const float4*)S.hs;
    const float4* cq = (const float4*)S.ctx;
    float acc = 0.f;
#pragma unroll 4
    for (int k4 = 0; k4 < 128; k4++) {
      float4 w = wrow[k4], x = hq[k4];
      acc = fmaf(w.x, x.x, acc); acc = fmaf(w.y, x.y, acc);
      acc = fmaf(w.z, x.z, acc); acc = fmaf(w.w, x.w, acc);
    }
#pragma unroll 4
    for (int k4 = 0; k4 < 128; k4++) {
      float4 w = wrow[128 + k4], x = cq[k4];
      acc = fmaf(w.x, x.x, acc); acc = fmaf(w.y, x.y, acc);
      acc = fmaf(w.z, x.z, acc); acc = fmaf(w.w, x.w, acc);
    }
    z = acc + bhc[tid];
  }
  // LayerNorm + tanh
  {
    float v1 = z, v2 = z * z;
    v1 += __shfl_xor(v1, 32); v2 += __shfl_xor(v2, 32);
    v1 += __shfl_xor(v1, 16); v2 += __shfl_xor(v2, 16);
    v1 += __shfl_xor(v1, 8);  v2 += __shfl_xor(v2, 8);
    v1 += __shfl_xor(v1, 4);  v2 += __shfl_xor(v2, 4);
    v1 += __shfl_xor(v1, 2);  v2 += __shfl_xor(v2, 2);
    v1 += __shfl_xor(v1, 1);  v2 += __shfl_xor(v2, 1);
    if ((tid & 63) == 0) { S.wred[(tid >> 6) * 2] = v1; S.wred[(tid >> 6) * 2 + 1] = v2; }
  }
  __syncthreads();
  {
    float s1 = 0.f, s2 = 0.f;
#pragma unroll
    for (int w = 0; w < 8; w++) { s1 += S.wred[2 * w]; s2 += S.wred[2 * w + 1]; }
    float m = s1 * (1.0f / 512.0f);
    float var = s2 * (1.0f / 512.0f) - m * m;
    float rstd = rsqrtf(var + 1e-5f);
    float e = ftanh((z - m) * rstd * gam[tid] + bet[tid]);
    st_f32(emb + (size_t)b * 512 + tid, e);
    S.es[tid] = e;
  }
  __syncthreads();
  if (tid < 128) {
    u64 q = pack4bf(S.es[4 * tid], S.es[4 * tid + 1], S.es[4 * tid + 2], S.es[4 * tid + 3]);
    st_u64c(ebfOut + (size_t)b * 128 + tid, q);
  }
}

// ---- logits: stage emb_bf into padded LDS; two 256-thread MFMA units/block ----
__device__ __forceinline__ void logits_stage(SmemU& SU, const u32* ebf) {
  int tid = threadIdx.x;
  const u64* src = (const u64*)ebf;
#pragma unroll
  for (int r = 0; r < 16; r++) {
    int i = r * 512 + tid;
    int mm = i >> 7, j = i & 127;
    u64 v = ld_u64c(src + i);
    *(u64*)&SU.ebf[mm * 520 + 4 * j] = v;
  }
  __syncthreads();
}

__device__ __forceinline__ void logits_tile(SmemU& SU,
    const unsigned short* __restrict__ vocab_bf, const float* __restrict__ vbias,
    float* __restrict__ out, int q)
{
  if (q >= NTILE) return;
  int n0 = q * 64;
  int ut = threadIdx.x & 255;
  int w = ut >> 6, l = ut & 63;
  int lm = l & 15, kb = l >> 4;
  int m = w * 16 + lm;
  f32x4 acc[4] = {};
  const unsigned short* arow = SU.ebf + m * 520 + kb * 8;
#pragma unroll 4
  for (int kt = 0; kt < 16; kt++) {
    short8 a = *(const short8*)(arow + kt * 32);
#pragma unroll
    for (int nt = 0; nt < 4; nt++) {
      const short8* bp = (const short8*)(vocab_bf + (size_t)(n0 + nt * 16 + lm) * 512);
      short8 bv = bp[kt * 4 + kb];
      acc[nt] = __builtin_amdgcn_mfma_f32_16x16x32_bf16(a, bv, acc[nt], 0, 0, 0);
    }
  }
  int rbase = w * 16 + kb * 4;  // C/D: col = lane&15, row = (lane>>4)*4 + reg
#pragma unroll
  for (int nt = 0; nt < 4; nt++) {
    int v = n0 + nt * 16 + lm;
    float bias = vbias[v];
#pragma unroll
    for (int r = 0; r < 4; r++) {
      out[(size_t)(rbase + r) * 32000 + v] = acc[nt][r] + bias;
    }
  }
}

// ---- persistent kernel ----
__global__ __launch_bounds__(NTHR, 1) void persist_k(
    const float* __restrict__ feats, const float* __restrict__ Wih, const float* __restrict__ Whh,
    const float* __restrict__ bih, const float* __restrict__ bhh,
    const float* __restrict__ Whc, const float* __restrict__ bhc,
    const float* __restrict__ gam, const float* __restrict__ bet,
    const float* __restrict__ vemb, const float* __restrict__ vbias,
    unsigned short* vocab_bf, float* hA, float* hB, float* cA, float* cB,
    float* emb, u64* ebf0, u64* ebf1, float* Mb, float* out, u32* bar)
{
  __shared__ SmemU SU;
  const int bid = blockIdx.x, tid = threadIdx.x;
  unsigned epoch = 0;
  u32* flags = bar;
  u32* go = bar + GRID * 32 + 16;

  // prologue: vocab fp32->bf16; state init; f-moments
  {
    const float4* vp = (const float4*)vemb;
    u64* ov = (u64*)vocab_bf;
    for (int i = bid * NTHR + tid; i < VV * DD / 4; i += GRID * NTHR)
      st_u64c(ov + i, pack4bf4(vp[i]));
  }
  {
    const float4* fp4 = (const float4*)feats;
    const float4* vp0 = (const float4*)vemb;
    for (int i = bid * NTHR + tid; i < BB * DD / 4; i += GRID * NTHR) {
      float4 f = fp4[i];
      st_u64c((u64*)cA + 2 * (size_t)i,     f2_to_u64(f.x, f.y));
      st_u64c((u64*)cA + 2 * (size_t)i + 1, f2_to_u64(f.z, f.w));
      st_u64c((u64*)hA + 2 * (size_t)i,     f2_to_u64(f.x, f.y));
      st_u64c((u64*)hA + 2 * (size_t)i + 1, f2_to_u64(f.z, f.w));
      float4 e = vp0[i & 127];
      st_u64c((u64*)emb + 2 * (size_t)i,     f2_to_u64(e.x, e.y));
      st_u64c((u64*)emb + 2 * (size_t)i + 1, f2_to_u64(e.z, e.w));
    }
  }
  if (bid < 64) {  // M_k[b] = (sum_i f_i^k) / k!
    float f = feats[(size_t)bid * 512 + tid];
    float part = 1.f;
#pragma unroll
    for (int k = 0; k < NP; k++) {
      float v = part;
      v += __shfl_xor(v, 32); v += __shfl_xor(v, 16); v += __shfl_xor(v, 8);
      v += __shfl_xor(v, 4);  v += __shfl_xor(v, 2);  v += __shfl_xor(v, 1);
      if ((tid & 63) == 0) SU.rec.sred[tid >> 6][k] = v;
      part *= f;
    }
    __syncthreads();
    if (tid < NP) {
      float s = 0.f;
#pragma unroll
      for (int w = 0; w < 8; w++) s += SU.rec.sred[w][tid];
      st_f32(Mb + bid * NP + tid, s * INVFACT[tid]);
    }
  }
  gridsync(flags, go, epoch);

  for (int t = 0; t < TT; t++) {
    float* ho = (t & 1) ? hB : hA; float* hn = (t & 1) ? hA : hB;
    const float* co = (t & 1) ? cB : cA; float* cn = (t & 1) ? cA : cB;
    u64* ebfOut = (t & 1) ? ebf0 : ebf1;
    const u32* ebfPrev = (const u32*)((t & 1) ? ebf1 : ebf0);

    // A: cell(t) on all 256 blocks
    cell_phase(SU, bid, Wih, Whh, bih, bhh, emb, ho, co, hn, cn);
    gridsync(flags, go, epoch);

    // B: rec(t) on 0..63 | logits(t-1) on 64..255
    if (bid < 64) {
      rec_phase(SU, bid, feats, hn, Mb, Whc, bhc, gam, bet, emb, ebfOut);
    } else if (t >= 1) {
      float* out_prev = out + (size_t)(t - 1) * BB * VV;
      logits_stage(SU, ebfPrev);
      int unit = (bid - 64) * 2 + (tid >> 8);
      logits_tile(SU, vocab_bf, vbias, out_prev, unit);
      if (unit < 116) logits_tile(SU, vocab_bf, vbias, out_prev, 384 + unit);
    }
    gridsync(flags, go, epoch);
  }

  // drain: logits(31) on all 256 blocks (512 units, 1 tile each; guard inside)
  {
    float* o31 = out + (size_t)(TT - 1) * BB * VV;
    logits_stage(SU, (const u32*)ebf0);  // t=31 wrote ebf0
    int unit = bid * 2 + (tid >> 8);
    logits_tile(SU, vocab_bf, vbias, o31, unit);
  }
}

extern "C" void kernel_launch(void* const* d_in, const int* in_sizes, int n_in,
                              void* d_out, int out_size, void* d_ws, size_t ws_size,
                              hipStream_t stream) {
  const float* feats = (const float*)d_in[0];
  const float* Wih   = (const float*)d_in[1];
  const float* Whh   = (const float*)d_in[2];
  const float* bih   = (const float*)d_in[3];
  const float* bhh   = (const float*)d_in[4];
  const float* Whc   = (const float*)d_in[5];
  const float* bhc   = (const float*)d_in[6];
  const float* gam   = (const float*)d_in[7];
  const float* bet   = (const float*)d_in[8];
  const float* vemb  = (const float*)d_in[9];
  const float* vbias = (const float*)d_in[10];
  float* out = (float*)d_out;

  char* p = (char*)d_ws;
  unsigned short* vocab_bf = (unsigned short*)p; p += (size_t)VV * DD * 2;  // 32.77MB
  float* hA  = (float*)p; p += (size_t)BB * DD * 4;
  float* hB  = (float*)p; p += (size_t)BB * DD * 4;
  float* cA  = (float*)p; p += (size_t)BB * DD * 4;
  float* cB  = (float*)p; p += (size_t)BB * DD * 4;
  float* emb = (float*)p; p += (size_t)BB * DD * 4;
  u64* ebf0  = (u64*)p;   p += (size_t)BB * DD * 2;
  u64* ebf1  = (u64*)p;   p += (size_t)BB * DD * 2;
  float* Mb  = (float*)p; p += 64 * NP * 4 + 112;
  u32* bar   = (u32*)p;   p += 8704 * 4;

  bar_init_k<<<17, 512, 0, stream>>>(bar);
  persist_k<<<GRID, NTHR, 0, stream>>>(feats, Wih, Whh, bih, bhh, Whc, bhc, gam, bet,
                                       vemb, vbias, vocab_bf, hA, hB, cA, cB, emb,
                                       ebf0, ebf1, Mb, out, bar);
}

// Round 7
// 4181.853 us; speedup vs baseline: 1.0038x; 1.0038x over previous
//
#include <hip/hip_runtime.h>

#define DD 512
#define BB 64
#define VV 32000
#define TT 32
#define GRID 256
#define NTHR 512
#define NP 25
#define NTILE 500

typedef __attribute__((ext_vector_type(8))) short short8;
typedef __attribute__((ext_vector_type(4))) float f32x4;
typedef unsigned long long u64;
typedef unsigned int u32;

__device__ __forceinline__ float sigm(float x) { return 1.0f / (1.0f + __expf(-x)); }
__device__ __forceinline__ float ftanh(float x) {
  float e = __expf(2.0f * x);
  return 1.0f - 2.0f / (e + 1.0f);
}
__device__ __forceinline__ unsigned short f2bf(float f) {
  u32 u = __float_as_uint(f);
  u = (u + 0x7FFFu + ((u >> 16) & 1u)) >> 16;
  return (unsigned short)u;
}
__device__ __forceinline__ u64 pack4bf(float a, float b, float c, float d) {
  return (u64)f2bf(a) | ((u64)f2bf(b) << 16) | ((u64)f2bf(c) << 32) | ((u64)f2bf(d) << 48);
}
__device__ __forceinline__ u64 pack4bf4(float4 v) { return pack4bf(v.x, v.y, v.z, v.w); }

// ---- coherent (LLC round-trip) accessors for mutable cross-block state ----
__device__ __forceinline__ void st_u32(u32* p, u32 v) {
  __hip_atomic_store(p, v, __ATOMIC_RELAXED, __HIP_MEMORY_SCOPE_AGENT);
}
__device__ __forceinline__ u32 ld_u32c(const u32* p) {
  return __hip_atomic_load(p, __ATOMIC_RELAXED, __HIP_MEMORY_SCOPE_AGENT);
}
__device__ __forceinline__ void st_u64c(u64* p, u64 v) {
  __hip_atomic_store(p, v, __ATOMIC_RELAXED, __HIP_MEMORY_SCOPE_AGENT);
}
__device__ __forceinline__ u64 ld_u64c(const u64* p) {
  return __hip_atomic_load(p, __ATOMIC_RELAXED, __HIP_MEMORY_SCOPE_AGENT);
}
__device__ __forceinline__ void st_f32(float* p, float v) { st_u32((u32*)p, __float_as_uint(v)); }
__device__ __forceinline__ float ld_f32(const float* p) { return __uint_as_float(ld_u32c((const u32*)p)); }
__device__ __forceinline__ float2 u64_to_f2(u64 v) {
  float2 r; r.x = __uint_as_float((u32)v); r.y = __uint_as_float((u32)(v >> 32)); return r;
}
__device__ __forceinline__ u64 f2_to_u64(float a, float b) {
  return (u64)__float_as_uint(a) | ((u64)__float_as_uint(b) << 32);
}

__device__ const float INVFACT[NP] = {
  1.0f, 1.0f, 0.5f, 1.6666667e-1f, 4.1666667e-2f, 8.3333333e-3f, 1.3888889e-3f,
  1.9841270e-4f, 2.4801587e-5f, 2.7557319e-6f, 2.7557319e-7f, 2.5052108e-8f,
  2.0876757e-9f, 1.6059044e-10f, 1.1470746e-11f, 7.6471637e-13f, 4.7794773e-14f,
  2.8114573e-15f, 1.5619207e-16f, 8.2206352e-18f, 4.1103176e-19f, 1.9572941e-20f,
  8.8967914e-22f, 3.8681702e-23f, 1.6117376e-24f
};

struct CellS {
  float4 xs4[16][129];
  float4 hs4[16][129];
  float gp[4][16][32];
  float ggv[16][32];
};
struct RecS {
  float fr[512], hs[512], wv[512], ctx[512], es[512];
  float mco[32], tco[32];
  float sred[8][32];
  float wred[16];
};
union SmemU { CellS cell; RecS rec; unsigned short ebf[64 * 520]; };

// ---- flag-array grid barrier (relaxed atomics only, leader+broadcast) ----
__device__ __forceinline__ void gridsync(u32* flags, u32* go, unsigned& epoch) {
  epoch++;
  asm volatile("s_waitcnt vmcnt(0) lgkmcnt(0)" ::: "memory");
  __syncthreads();
  int tid = threadIdx.x, bid = blockIdx.x;
  if (bid == 0) {
    if (tid == 0) st_u32(flags, epoch);
    int ok;
    do {
      u32 f = (tid < GRID) ? ld_u32c(flags + (size_t)tid * 32) : epoch;
      ok = __syncthreads_and((int)(f >= epoch));
    } while (!ok);
    if (tid == 0) st_u32(go, epoch);
  } else {
    if (tid == 0) {
      st_u32(flags + (size_t)bid * 32, epoch);
      while (ld_u32c(go) < epoch) __builtin_amdgcn_s_sleep(8);
    }
    __syncthreads();
  }
}

__global__ void bar_init_k(u32* bar) {
  int i = blockIdx.x * 512 + threadIdx.x;
  if (i < 8704) bar[i] = 0u;
}

// ---- phase A: LSTM cell, fp32 VALU ----
__device__ __forceinline__ void cell_phase(SmemU& SU, int bid,
    const float* __restrict__ Wih, const float* __restrict__ Whh,
    const float* __restrict__ bih, const float* __restrict__ bhh,
    const float* emb, const float* h_old, const float* c_old,
    float* h_new, float* c_new)
{
  CellS& S = SU.cell;
  int tid = threadIdx.x;
  int bg = bid >> 6, cg = bid & 63;
  int b0 = bg * 16, d0 = cg * 8;
  const u64* ep = (const u64*)emb;
  const u64* hp = (const u64*)h_old;
  for (int i = tid; i < 4096; i += NTHR) {
    int b = i >> 8, k2 = i & 255;
    float2 e2 = u64_to_f2(ld_u64c(ep + (size_t)(b0 + b) * 256 + k2));
    float2 h2 = u64_to_f2(ld_u64c(hp + (size_t)(b0 + b) * 256 + k2));
    ((float2*)&S.xs4[b][0])[k2] = e2;
    ((float2*)&S.hs4[b][0])[k2] = h2;
  }
  __syncthreads();
  {
    int ks = tid >> 7, sub = tid & 127, b = sub >> 3, dl = sub & 7;
    const float4* wi0 = (const float4*)(Wih + (size_t)(0 * 512 + d0 + dl) * 512) + ks * 32;
    const float4* wi1 = (const float4*)(Wih + (size_t)(1 * 512 + d0 + dl) * 512) + ks * 32;
    const float4* wi2 = (const float4*)(Wih + (size_t)(2 * 512 + d0 + dl) * 512) + ks * 32;
    const float4* wi3 = (const float4*)(Wih + (size_t)(3 * 512 + d0 + dl) * 512) + ks * 32;
    const float4* wh0 = (const float4*)(Whh + (size_t)(0 * 512 + d0 + dl) * 512) + ks * 32;
    const float4* wh1 = (const float4*)(Whh + (size_t)(1 * 512 + d0 + dl) * 512) + ks * 32;
    const float4* wh2 = (const float4*)(Whh + (size_t)(2 * 512 + d0 + dl) * 512) + ks * 32;
    const float4* wh3 = (const float4*)(Whh + (size_t)(3 * 512 + d0 + dl) * 512) + ks * 32;
    const float4* xr = &S.xs4[b][ks * 32];
    const float4* hr = &S.hs4[b][ks * 32];
    float a0 = 0.f, a1 = 0.f, a2 = 0.f, a3 = 0.f;
#pragma unroll 4
    for (int j = 0; j < 32; j++) {
      float4 xv = xr[j], hv = hr[j];
      float4 w;
      w = wi0[j]; a0 = fmaf(w.x, xv.x, a0); a0 = fmaf(w.y, xv.y, a0); a0 = fmaf(w.z, xv.z, a0); a0 = fmaf(w.w, xv.w, a0);
      w = wh0[j]; a0 = fmaf(w.x, hv.x, a0); a0 = fmaf(w.y, hv.y, a0); a0 = fmaf(w.z, hv.z, a0); a0 = fmaf(w.w, hv.w, a0);
      w = wi1[j]; a1 = fmaf(w.x, xv.x, a1); a1 = fmaf(w.y, xv.y, a1); a1 = fmaf(w.z, xv.z, a1); a1 = fmaf(w.w, xv.w, a1);
      w = wh1[j]; a1 = fmaf(w.x, hv.x, a1); a1 = fmaf(w.y, hv.y, a1); a1 = fmaf(w.z, hv.z, a1); a1 = fmaf(w.w, hv.w, a1);
      w = wi2[j]; a2 = fmaf(w.x, xv.x, a2); a2 = fmaf(w.y, xv.y, a2); a2 = fmaf(w.z, xv.z, a2); a2 = fmaf(w.w, xv.w, a2);
      w = wh2[j]; a2 = fmaf(w.x, hv.x, a2); a2 = fmaf(w.y, hv.y, a2); a2 = fmaf(w.z, hv.z, a2); a2 = fmaf(w.w, hv.w, a2);
      w = wi3[j]; a3 = fmaf(w.x, xv.x, a3); a3 = fmaf(w.y, xv.y, a3); a3 = fmaf(w.z, xv.z, a3); a3 = fmaf(w.w, xv.w, a3);
      w = wh3[j]; a3 = fmaf(w.x, hv.x, a3); a3 = fmaf(w.y, hv.y, a3); a3 = fmaf(w.z, hv.z, a3); a3 = fmaf(w.w, hv.w, a3);
    }
    S.gp[ks][b][dl * 4 + 0] = a0;
    S.gp[ks][b][dl * 4 + 1] = a1;
    S.gp[ks][b][dl * 4 + 2] = a2;
    S.gp[ks][b][dl * 4 + 3] = a3;
  }
  __syncthreads();
  {
    int b = tid >> 5, rg = tid & 31;
    float s = S.gp[0][b][rg] + S.gp[1][b][rg] + S.gp[2][b][rg] + S.gp[3][b][rg];
    int dl = rg >> 2, g = rg & 3;
    int r = g * 512 + d0 + dl;
    s += bih[r] + bhh[r];
    S.ggv[b][rg] = s;
  }
  __syncthreads();
  if (tid < 128) {
    int b = tid >> 3, dl = tid & 7;
    float gi = S.ggv[b][dl * 4 + 0];
    float gf = S.ggv[b][dl * 4 + 1];
    float gg = S.ggv[b][dl * 4 + 2];
    float go = S.ggv[b][dl * 4 + 3];
    size_t idx = (size_t)(b0 + b) * 512 + d0 + dl;
    float c2 = sigm(gf) * ld_f32(c_old + idx) + sigm(gi) * ftanh(gg);
    st_f32(c_new + idx, c2);
    st_f32(h_new + idx, sigm(go) * ftanh(c2));
  }
}

// ---- phase B (blocks 0..63): fp32 Taylor attention + zgemm + LN ----
__device__ __forceinline__ void rec_phase(SmemU& SU, int b,
    const float* __restrict__ feats, const float* h, const float* Mb,
    const float* __restrict__ Whc, const float* __restrict__ bhc,
    const float* __restrict__ gam, const float* __restrict__ bet,
    float* emb, u64* ebfOut)
{
  RecS& S = SU.rec;
  int tid = threadIdx.x;
  if (tid < 256) {
    float2 h2 = u64_to_f2(ld_u64c((const u64*)h + (size_t)b * 256 + tid));
    S.hs[2 * tid] = h2.x; S.hs[2 * tid + 1] = h2.y;
  } else {
    int t2 = tid - 256;
    float2 f2 = ((const float2*)feats)[(size_t)b * 256 + t2];
    S.fr[2 * t2] = f2.x; S.fr[2 * t2 + 1] = f2.y;
  }
  if (tid < NP) S.mco[tid] = ld_f32(Mb + b * NP + tid);
  __syncthreads();
  float hj = S.hs[tid];
  float fi = S.fr[tid];
  {
    float Z = S.mco[NP - 1];
#pragma unroll
    for (int k = NP - 2; k >= 0; k--) Z = fmaf(Z, hj, S.mco[k]);
    S.wv[tid] = fi / Z;
  }
  __syncthreads();
  {
    float part = S.wv[tid];
#pragma unroll
    for (int k = 0; k < NP; k++) {
      float v = part;
      v += __shfl_xor(v, 32); v += __shfl_xor(v, 16); v += __shfl_xor(v, 8);
      v += __shfl_xor(v, 4);  v += __shfl_xor(v, 2);  v += __shfl_xor(v, 1);
      if ((tid & 63) == 0) S.sred[tid >> 6][k] = v;
      part *= hj;
    }
  }
  __syncthreads();
  if (tid < NP) {
    float s = 0.f;
#pragma unroll
    for (int w = 0; w < 8; w++) s += S.sred[w][tid];
    S.tco[tid] = s * INVFACT[tid];
  }
  __syncthreads();
  {
    float C = S.tco[NP - 1];
#pragma unroll
    for (int k = NP - 2; k >= 0; k--) C = fmaf(C, fi, S.tco[k]);
    S.ctx[tid] = C;
  }
  __syncthreads();
  float z;
  {
    const float4* wrow = (const float4*)(Whc + (size_t)tid * 1024);
    const float4* hq = (const float4*)S.hs;
    const float4* cq = (const float4*)S.ctx;
    float acc = 0.f;
#pragma unroll 4
    for (int k4 = 0; k4 < 128; k4++) {
      float4 w = wrow[k4], x = hq[k4];
      acc = fmaf(w.x, x.x, acc); acc = fmaf(w.y, x.y, acc);
      acc = fmaf(w.z, x.z, acc); acc = fmaf(w.w, x.w, acc);
    }
#pragma unroll 4
    for (int k4 = 0; k4 < 128; k4++) {
      float4 w = wrow[128 + k4], x = cq[k4];
      acc = fmaf(w.x, x.x, acc); acc = fmaf(w.y, x.y, acc);
      acc = fmaf(w.z, x.z, acc); acc = fmaf(w.w, x.w, acc);
    }
    z = acc + bhc[tid];
  }
  {
    float v1 = z, v2 = z * z;
    v1 += __shfl_xor(v1, 32); v2 += __shfl_xor(v2, 32);
    v1 += __shfl_xor(v1, 16); v2 += __shfl_xor(v2, 16);
    v1 += __shfl_xor(v1, 8);  v2 += __shfl_xor(v2, 8);
    v1 += __shfl_xor(v1, 4);  v2 += __shfl_xor(v2, 4);
    v1 += __shfl_xor(v1, 2);  v2 += __shfl_xor(v2, 2);
    v1 += __shfl_xor(v1, 1);  v2 += __shfl_xor(v2, 1);
    if ((tid & 63) == 0) { S.wred[(tid >> 6) * 2] = v1; S.wred[(tid >> 6) * 2 + 1] = v2; }
  }
  __syncthreads();
  {
    float s1 = 0.f, s2 = 0.f;
#pragma unroll
    for (int w = 0; w < 8; w++) { s1 += S.wred[2 * w]; s2 += S.wred[2 * w + 1]; }
    float m = s1 * (1.0f / 512.0f);
    float var = s2 * (1.0f / 512.0f) - m * m;
    float rstd = rsqrtf(var + 1e-5f);
    float e = ftanh((z - m) * rstd * gam[tid] + bet[tid]);
    st_f32(emb + (size_t)b * 512 + tid, e);
    S.es[tid] = e;
  }
  __syncthreads();
  if (tid < 128) {
    u64 q = pack4bf(S.es[4 * tid], S.es[4 * tid + 1], S.es[4 * tid + 2], S.es[4 * tid + 3]);
    st_u64c(ebfOut + (size_t)b * 128 + tid, q);
  }
}

// ---- logits: stage emb_bf into padded LDS; two 256-thread MFMA units/block ----
__device__ __forceinline__ void logits_stage(SmemU& SU, const u32* ebf) {
  int tid = threadIdx.x;
  const u64* src = (const u64*)ebf;
#pragma unroll
  for (int r = 0; r < 16; r++) {
    int i = r * 512 + tid;
    int mm = i >> 7, j = i & 127;
    u64 v = ld_u64c(src + i);
    *(u64*)&SU.ebf[mm * 520 + 4 * j] = v;
  }
  __syncthreads();
}

// double-buffered B loads (refill the just-consumed buffer) + NT C stores
__device__ __forceinline__ void logits_tile(SmemU& SU,
    const unsigned short* __restrict__ vocab_bf, const float* __restrict__ vbias,
    float* __restrict__ out, int q)
{
  if (q >= NTILE) return;
  int n0 = q * 64;
  int ut = threadIdx.x & 255;
  int w = ut >> 6, l = ut & 63;
  int lm = l & 15, kb = l >> 4;
  int m = w * 16 + lm;
  f32x4 acc[4] = {};
  const unsigned short* arow = SU.ebf + m * 520 + kb * 8;
  const short8* bp0 = (const short8*)(vocab_bf + (size_t)(n0 +  0 + lm) * 512) + kb;
  const short8* bp1 = (const short8*)(vocab_bf + (size_t)(n0 + 16 + lm) * 512) + kb;
  const short8* bp2 = (const short8*)(vocab_bf + (size_t)(n0 + 32 + lm) * 512) + kb;
  const short8* bp3 = (const short8*)(vocab_bf + (size_t)(n0 + 48 + lm) * 512) + kb;
  short8 bA[4], bB[4];
  bA[0] = bp0[0]; bA[1] = bp1[0]; bA[2] = bp2[0]; bA[3] = bp3[0];
  bB[0] = bp0[4]; bB[1] = bp1[4]; bB[2] = bp2[4]; bB[3] = bp3[4];
#pragma unroll
  for (int kt = 0; kt < 16; kt++) {
    short8 a = *(const short8*)(arow + kt * 32);
    short8* bc = (kt & 1) ? bB : bA;   // holds kt's fragments
    acc[0] = __builtin_amdgcn_mfma_f32_16x16x32_bf16(a, bc[0], acc[0], 0, 0, 0);
    acc[1] = __builtin_amdgcn_mfma_f32_16x16x32_bf16(a, bc[1], acc[1], 0, 0, 0);
    acc[2] = __builtin_amdgcn_mfma_f32_16x16x32_bf16(a, bc[2], acc[2], 0, 0, 0);
    acc[3] = __builtin_amdgcn_mfma_f32_16x16x32_bf16(a, bc[3], acc[3], 0, 0, 0);
    if (kt < 14) {                     // refill the buffer just consumed with kt+2
      int o = (kt + 2) * 4;
      bc[0] = bp0[o]; bc[1] = bp1[o]; bc[2] = bp2[o]; bc[3] = bp3[o];
    }
  }
  int rbase = w * 16 + kb * 4;  // C/D: col = lane&15, row = (lane>>4)*4 + reg
#pragma unroll
  for (int nt = 0; nt < 4; nt++) {
    int v = n0 + nt * 16 + lm;
    float bias = vbias[v];
#pragma unroll
    for (int r = 0; r < 4; r++) {
      __builtin_nontemporal_store(acc[nt][r] + bias,
                                  &out[(size_t)(rbase + r) * 32000 + v]);
    }
  }
}

// ---- persistent kernel ----
__global__ __launch_bounds__(NTHR, 1) void persist_k(
    const float* __restrict__ feats, const float* __restrict__ Wih, const float* __restrict__ Whh,
    const float* __restrict__ bih, const float* __restrict__ bhh,
    const float* __restrict__ Whc, const float* __restrict__ bhc,
    const float* __restrict__ gam, const float* __restrict__ bet,
    const float* __restrict__ vemb, const float* __restrict__ vbias,
    unsigned short* vocab_bf, float* hA, float* hB, float* cA, float* cB,
    float* emb, u64* ebf0, u64* ebf1, float* Mb, float* out, u32* bar)
{
  __shared__ SmemU SU;
  const int bid = blockIdx.x, tid = threadIdx.x;
  unsigned epoch = 0;
  u32* flags = bar;
  u32* go = bar + GRID * 32 + 16;

  // prologue: vocab fp32->bf16; state init; f-moments
  {
    const float4* vp = (const float4*)vemb;
    u64* ov = (u64*)vocab_bf;
    for (int i = bid * NTHR + tid; i < VV * DD / 4; i += GRID * NTHR)
      st_u64c(ov + i, pack4bf4(vp[i]));
  }
  {
    const float4* fp4 = (const float4*)feats;
    const float4* vp0 = (const float4*)vemb;
    for (int i = bid * NTHR + tid; i < BB * DD / 4; i += GRID * NTHR) {
      float4 f = fp4[i];
      st_u64c((u64*)cA + 2 * (size_t)i,     f2_to_u64(f.x, f.y));
      st_u64c((u64*)cA + 2 * (size_t)i + 1, f2_to_u64(f.z, f.w));
      st_u64c((u64*)hA + 2 * (size_t)i,     f2_to_u64(f.x, f.y));
      st_u64c((u64*)hA + 2 * (size_t)i + 1, f2_to_u64(f.z, f.w));
      float4 e = vp0[i & 127];
      st_u64c((u64*)emb + 2 * (size_t)i,     f2_to_u64(e.x, e.y));
      st_u64c((u64*)emb + 2 * (size_t)i + 1, f2_to_u64(e.z, e.w));
    }
  }
  if (bid < 64) {  // M_k[b] = (sum_i f_i^k) / k!
    float f = feats[(size_t)bid * 512 + tid];
    float part = 1.f;
#pragma unroll
    for (int k = 0; k < NP; k++) {
      float v = part;
      v += __shfl_xor(v, 32); v += __shfl_xor(v, 16); v += __shfl_xor(v, 8);
      v += __shfl_xor(v, 4);  v += __shfl_xor(v, 2);  v += __shfl_xor(v, 1);
      if ((tid & 63) == 0) SU.rec.sred[tid >> 6][k] = v;
      part *= f;
    }
    __syncthreads();
    if (tid < NP) {
      float s = 0.f;
#pragma unroll
      for (int w = 0; w < 8; w++) s += SU.rec.sred[w][tid];
      st_f32(Mb + bid * NP + tid, s * INVFACT[tid]);
    }
  }
  gridsync(flags, go, epoch);

  for (int t = 0; t < TT; t++) {
    float* ho = (t & 1) ? hB : hA; float* hn = (t & 1) ? hA : hB;
    const float* co = (t & 1) ? cB : cA; float* cn = (t & 1) ? cA : cB;
    u64* ebfOut = (t & 1) ? ebf0 : ebf1;
    const u32* ebfPrev = (const u32*)((t & 1) ? ebf1 : ebf0);

    // A: cell(t) on all 256 blocks
    cell_phase(SU, bid, Wih, Whh, bih, bhh, emb, ho, co, hn, cn);
    gridsync(flags, go, epoch);

    // B: rec(t) on 0..63 | logits(t-1) on 64..255
    if (bid < 64) {
      rec_phase(SU, bid, feats, hn, Mb, Whc, bhc, gam, bet, emb, ebfOut);
    } else if (t >= 1) {
      float* out_prev = out + (size_t)(t - 1) * BB * VV;
      logits_stage(SU, ebfPrev);
      int unit = (bid - 64) * 2 + (tid >> 8);
      logits_tile(SU, vocab_bf, vbias, out_prev, unit);
      if (unit < 116) logits_tile(SU, vocab_bf, vbias, out_prev, 384 + unit);
    }
    gridsync(flags, go, epoch);
  }

  // drain: logits(31) on all 256 blocks
  {
    float* o31 = out + (size_t)(TT - 1) * BB * VV;
    logits_stage(SU, (const u32*)ebf0);  // t=31 wrote ebf0
    int unit = bid * 2 + (tid >> 8);
    logits_tile(SU, vocab_bf, vbias, o31, unit);
  }
}

extern "C" void kernel_launch(void* const* d_in, const int* in_sizes, int n_in,
                              void* d_out, int out_size, void* d_ws, size_t ws_size,
                              hipStream_t stream) {
  const float* feats = (const float*)d_in[0];
  const float* Wih   = (const float*)d_in[1];
  const float* Whh   = (const float*)d_in[2];
  const float* bih   = (const float*)d_in[3];
  const float* bhh   = (const float*)d_in[4];
  const float* Whc   = (const float*)d_in[5];
  const float* bhc   = (const float*)d_in[6];
  const float* gam   = (const float*)d_in[7];
  const float* bet   = (const float*)d_in[8];
  const float* vemb  = (const float*)d_in[9];
  const float* vbias = (const float*)d_in[10];
  float* out = (float*)d_out;

  char* p = (char*)d_ws;
  unsigned short* vocab_bf = (unsigned short*)p; p += (size_t)VV * DD * 2;  // 32.77MB
  float* hA  = (float*)p; p += (size_t)BB * DD * 4;
  float* hB  = (float*)p; p += (size_t)BB * DD * 4;
  float* cA  = (float*)p; p += (size_t)BB * DD * 4;
  float* cB  = (float*)p; p += (size_t)BB * DD * 4;
  float* emb = (float*)p; p += (size_t)BB * DD * 4;
  u64* ebf0  = (u64*)p;   p += (size_t)BB * DD * 2;
  u64* ebf1  = (u64*)p;   p += (size_t)BB * DD * 2;
  float* Mb  = (float*)p; p += 64 * NP * 4 + 112;
  u32* bar   = (u32*)p;   p += 8704 * 4;

  bar_init_k<<<17, 512, 0, stream>>>(bar);
  persist_k<<<GRID, NTHR, 0, stream>>>(feats, Wih, Whh, bih, bhh, Whc, bhc, gam, bet,
                                       vemb, vbias, vocab_bf, hA, hB, cA, cB, emb,
                                       ebf0, ebf1, Mb, out, bar);
}